// Round 2
// baseline (271.590 us; speedup 1.0000x reference)
//
#include <hip/hip_runtime.h>

// Problem constants (fixed by the reference setup_inputs)
#define N_PTS 8192   // points per batch
#define M_Q   2048   // query points per batch
#define C_F   64     // feature channels
#define NS    32     // nsample
#define B_SZ  8      // batch

// ---------------------------------------------------------------------------
// K1: ball query. One wave (64 lanes) per query point. Scan xyz[b] in chunks
// of 64, ballot the in-radius predicate, compact hit indices in ascending
// order via popcount-prefix, early-exit once 32 found.
//
// NUMERICS: must match the numpy reference's f32 formula bit-for-bit:
//   d2 = (q2 + p2) - 2*qp, with q2/p2/qp each accumulated left-to-right in
//   f32, NO fma contraction (numpy doesn't fuse). Round-1 failure (absmax
//   5.36 ~ one wrong feature gather) was exact-f64 dist disagreeing with the
//   reference's cancellation-prone f32 formula on ~boundary pairs.
// ---------------------------------------------------------------------------
__global__ __launch_bounds__(256) void qb_kernel(
    const float* __restrict__ xyz, const float* __restrict__ nxyz,
    int* __restrict__ idx_out)
{
#pragma clang fp contract(off)
    const int lane = threadIdx.x & 63;
    const int q    = blockIdx.x * 4 + (threadIdx.x >> 6); // global query id, 0..B*M-1
    const int b    = q >> 11;                             // M_Q = 2048
    const float* __restrict__ xb = xyz + (size_t)b * (N_PTS * 3);
    const float* __restrict__ qp = nxyz + (size_t)q * 3;
    const float qx = qp[0];
    const float qy = qp[1];
    const float qz = qp[2];
    const float q2 = (qx * qx + qy * qy) + qz * qz;   // matches np.sum order
    int* __restrict__ out = idx_out + (size_t)q * NS;

    int  cnt = 0;
    int  first_idx = 0;
    bool have_first = false;

    for (int base = 0; base < N_PTS; base += 64) {
        const int n = base + lane;
        const float* __restrict__ p = xb + n * 3;
        const float p0 = p[0], p1 = p[1], p2v = p[2];
        const float p2sum = (p0 * p0 + p1 * p1) + p2v * p2v;     // np.sum order
        const float qpdot = (qx * p0 + qy * p1) + qz * p2v;      // np.einsum order
        const float t  = q2 + p2sum;
        const float d2 = t - 2.0f * qpdot;                       // ref formula
        const bool pred = d2 < 1.0f;
        const unsigned long long mask = __ballot(pred);
        if (mask) {
            if (!have_first) {
                first_idx = base + __ffsll((unsigned long long)mask) - 1;
                have_first = true;
            }
            if (pred) {
                const int pos = cnt + (int)__popcll(mask & ((1ull << lane) - 1ull));
                if (pos < NS) out[pos] = n;
            }
            cnt += (int)__popcll(mask);
            if (cnt >= NS) break;   // wave-uniform (mask/cnt are uniform)
        }
    }
    if (cnt < NS) {
        // pad [cnt, NS) with the first (lowest) valid index
        for (int p = cnt + lane; p < NS; p += 64) out[p] = first_idx;
    }
}

// ---------------------------------------------------------------------------
// K2: gather + concat. Block = 256 threads = 8 queries x 32 samples.
// For each (q, s): n = idx[q*32+s]. Write 3 xyz-diff channels then 64
// gathered feature channels. Per channel a block writes 8*32 = 256
// consecutive floats (1 KB) -> fully coalesced. Feature gathers hit a hot
// low-index region (first-32-ascending selection) -> L2-resident.
// Output layout: out[((b*67 + c)*M + m)*32 + s].
// ---------------------------------------------------------------------------
__global__ __launch_bounds__(256) void gather_kernel(
    const float* __restrict__ xyz, const float* __restrict__ nxyz,
    const float* __restrict__ feat, const int* __restrict__ idx,
    float* __restrict__ out)
{
    const int s  = threadIdx.x & 31;
    const int mi = threadIdx.x >> 5;            // 0..7
    const int q  = blockIdx.x * 8 + mi;         // global query id
    const int b  = q >> 11;
    const int m  = q & (M_Q - 1);

    const int n = idx[q * NS + s];              // coalesced (256 consecutive ints)

    const float* __restrict__ xb = xyz + (size_t)b * (N_PTS * 3) + (size_t)n * 3;
    const float* __restrict__ qp = nxyz + (size_t)q * 3;

    const size_t cstride = (size_t)M_Q * NS;    // 65536
    size_t o = ((size_t)b * 67 * M_Q + m) * NS + s;

    out[o]               = xb[0] - qp[0];
    out[o + cstride]     = xb[1] - qp[1];
    out[o + 2 * cstride] = xb[2] - qp[2];
    o += 3 * cstride;

    const float* __restrict__ fb = feat + (size_t)b * C_F * N_PTS + n;
#pragma unroll 8
    for (int c = 0; c < C_F; ++c) {
        out[o] = fb[(size_t)c * N_PTS];
        o += cstride;
    }
}

extern "C" void kernel_launch(void* const* d_in, const int* in_sizes, int n_in,
                              void* d_out, int out_size, void* d_ws, size_t ws_size,
                              hipStream_t stream)
{
    const float* xyz  = (const float*)d_in[0];   // (B, N, 3)
    const float* nxyz = (const float*)d_in[1];   // (B, M, 3)
    const float* feat = (const float*)d_in[2];   // (B, C, N)
    float* out = (float*)d_out;                  // (B, 67, M, 32)
    int* idx = (int*)d_ws;                       // (B*M, 32) scratch: 2 MB

    const int Q = B_SZ * M_Q;                    // 16384 queries

    qb_kernel<<<Q / 4, 256, 0, stream>>>(xyz, nxyz, idx);
    gather_kernel<<<Q / 8, 256, 0, stream>>>(xyz, nxyz, feat, idx, out);
}

// Round 3
// 189.934 us; speedup vs baseline: 1.4299x; 1.4299x over previous
//
#include <hip/hip_runtime.h>

// Problem constants (fixed by the reference setup_inputs)
#define N_PTS 8192   // points per batch
#define M_Q   2048   // query points per batch
#define C_F   64     // feature channels
#define NS    32     // nsample
#define B_SZ  8      // batch

// ---------------------------------------------------------------------------
// K1: ball query. One wave per query. v2: macro-chunks of 256 points — all 12
// point-loads issued before the 4 ballot/compact rounds, so memory latency is
// hidden by MLP instead of serialized per-64-point ballot round-trips.
//
// NUMERICS (pinned, round-2 passed absmax=0): must match numpy's f32 formula
// bit-for-bit: d2 = (q2 + p2) - 2*qp, each partial left-to-right f32, no fma.
// ---------------------------------------------------------------------------
__global__ __launch_bounds__(256) void qb_kernel(
    const float* __restrict__ xyz, const float* __restrict__ nxyz,
    int* __restrict__ idx_out)
{
#pragma clang fp contract(off)
    const int lane = threadIdx.x & 63;
    const int q    = blockIdx.x * 4 + (threadIdx.x >> 6); // 0..B*M-1
    const int b    = q >> 11;                             // M_Q = 2048
    const float* __restrict__ xb = xyz + (size_t)b * (N_PTS * 3);
    const float* __restrict__ qp = nxyz + (size_t)q * 3;
    const float qx = qp[0];
    const float qy = qp[1];
    const float qz = qp[2];
    const float q2 = (qx * qx + qy * qy) + qz * qz;   // np.sum order
    int* __restrict__ out = idx_out + (size_t)q * NS;

    int  cnt = 0;
    int  first_idx = 0;
    bool have_first = false;

    for (int base = 0; base < N_PTS && cnt < NS; base += 256) {
        float d2[4];
#pragma unroll
        for (int cc = 0; cc < 4; ++cc) {
            const int n = base + cc * 64 + lane;
            const float* __restrict__ p = xb + n * 3;
            const float p0 = p[0], p1 = p[1], p2v = p[2];
            const float p2sum = (p0 * p0 + p1 * p1) + p2v * p2v; // np order
            const float qpdot = (qx * p0 + qy * p1) + qz * p2v;  // np order
            d2[cc] = (q2 + p2sum) - 2.0f * qpdot;                // ref formula
        }
#pragma unroll
        for (int cc = 0; cc < 4; ++cc) {
            if (cnt >= NS) break;                  // wave-uniform
            const bool pred = d2[cc] < 1.0f;
            const unsigned long long mask = __ballot(pred);
            if (mask) {
                if (!have_first) {
                    first_idx = base + cc * 64 + __ffsll(mask) - 1;
                    have_first = true;
                }
                if (pred) {
                    const int pos = cnt + (int)__popcll(mask & ((1ull << lane) - 1ull));
                    if (pos < NS) out[pos] = base + cc * 64 + lane;
                }
                cnt += (int)__popcll(mask);
            }
        }
    }
    if (cnt < NS) {
        for (int p = cnt + lane; p < NS; p += 64) out[p] = first_idx;
    }
}

// ---------------------------------------------------------------------------
// K2: transpose feat (b,c,n) -> featT (b,n,c) so per-sample channel reads are
// 256 contiguous bytes. Standard 64x64 LDS tile, stride 65 (2-way = free).
// ---------------------------------------------------------------------------
__global__ __launch_bounds__(256) void transpose_kernel(
    const float* __restrict__ feat, float* __restrict__ featT)
{
    __shared__ float lds[C_F * 65];
    const int b  = blockIdx.x >> 7;        // 128 n-tiles per batch
    const int n0 = (blockIdx.x & 127) * 64;

    {
        const int c4 = threadIdx.x >> 6;   // 0..3
        const int nn = threadIdx.x & 63;
#pragma unroll
        for (int k = 0; k < 16; ++k) {
            const int c = k * 4 + c4;
            lds[c * 65 + nn] = feat[((size_t)b * C_F + c) * N_PTS + n0 + nn];
        }
    }
    __syncthreads();
    {
        const int n4 = threadIdx.x >> 6;   // 0..3
        const int c  = threadIdx.x & 63;
#pragma unroll
        for (int k = 0; k < 16; ++k) {
            const int nn = k * 4 + n4;
            featT[((size_t)b * N_PTS + n0 + nn) * C_F + c] = lds[c * 65 + nn];
        }
    }
}

// ---------------------------------------------------------------------------
// K3: gather + concat. One block (256 threads) per query. 8 lanes per sample:
// each lane reads 2 float4s of featT[b,n,:] (per wave-load: 16 fully-used
// 64-B lines, amplification 1.0). Stage into LDS[row][sample] (row = output
// channel, stride 33 => all write/read phases <=2-way bank = free), then
// write out coalesced: out[((b*67 + row)*M + m)*32 + s].
// ---------------------------------------------------------------------------
__global__ __launch_bounds__(256) void gather_kernel(
    const float* __restrict__ xyz, const float* __restrict__ nxyz,
    const float* __restrict__ featT, const int* __restrict__ idx,
    float* __restrict__ out)
{
    __shared__ float lds[67 * 33];
    const int q = blockIdx.x;
    const int b = q >> 11;
    const int m = q & (M_Q - 1);

    // phase 1: gather 64 channels + 3 xyz-diffs for the 32 samples
    {
        const int p = threadIdx.x >> 3;    // sample 0..31
        const int j = threadIdx.x & 7;     // lane-within-sample
        const int n = idx[q * NS + p];
        const float* __restrict__ fb = featT + ((size_t)b * N_PTS + n) * C_F;
#pragma unroll
        for (int k = 0; k < 2; ++k) {
            const int c = k * 32 + j * 4;                   // 16B-aligned
            const float4 v = *(const float4*)(fb + c);
            lds[(3 + c + 0) * 33 + p] = v.x;
            lds[(3 + c + 1) * 33 + p] = v.y;
            lds[(3 + c + 2) * 33 + p] = v.z;
            lds[(3 + c + 3) * 33 + p] = v.w;
        }
        if (j == 0) {
            const float* __restrict__ xb = xyz + (size_t)b * (N_PTS * 3) + (size_t)n * 3;
            const float* __restrict__ qp = nxyz + (size_t)q * 3;
            lds[0 * 33 + p] = xb[0] - qp[0];
            lds[1 * 33 + p] = xb[1] - qp[1];
            lds[2 * 33 + p] = xb[2] - qp[2];
        }
    }
    __syncthreads();

    // phase 2: coalesced writes, 67 channels x 32 samples = 2144 floats
    {
        const size_t obase = ((size_t)b * 67 * M_Q + m) * NS;
#pragma unroll
        for (int it = 0; it < 9; ++it) {
            const int e = it * 256 + threadIdx.x;
            if (e < 67 * NS) {
                const int row = e >> 5;
                const int p   = e & 31;
                out[obase + (size_t)row * (M_Q * NS) + p] = lds[row * 33 + p];
            }
        }
    }
}

extern "C" void kernel_launch(void* const* d_in, const int* in_sizes, int n_in,
                              void* d_out, int out_size, void* d_ws, size_t ws_size,
                              hipStream_t stream)
{
    const float* xyz  = (const float*)d_in[0];   // (B, N, 3)
    const float* nxyz = (const float*)d_in[1];   // (B, M, 3)
    const float* feat = (const float*)d_in[2];   // (B, C, N)
    float* out = (float*)d_out;                  // (B, 67, M, 32)

    int*   idx   = (int*)d_ws;                             // 2 MB
    float* featT = (float*)((char*)d_ws + (4 << 20));      // 16.8 MB

    const int Q = B_SZ * M_Q;                    // 16384 queries

    transpose_kernel<<<B_SZ * 128, 256, 0, stream>>>(feat, featT);
    qb_kernel<<<Q / 4, 256, 0, stream>>>(xyz, nxyz, idx);
    gather_kernel<<<Q, 256, 0, stream>>>(xyz, nxyz, featT, idx, out);
}

// Round 4
// 178.466 us; speedup vs baseline: 1.5218x; 1.0643x over previous
//
#include <hip/hip_runtime.h>

// Problem constants (fixed by the reference setup_inputs)
#define N_PTS 8192   // points per batch
#define M_Q   2048   // query points per batch
#define C_F   64     // feature channels
#define NS    32     // nsample
#define B_SZ  8      // batch

// ---------------------------------------------------------------------------
// K1: prep.
//  blocks [0, 1024):   transpose feat (b,c,n) -> featT (b,n,c). 64x64 LDS
//                      tile, stride 65 (2-way bank = free).
//  blocks [1024, 1280): xyz4[b*N+n] = (x, y, z, p2sum). p2sum computed in the
//                      exact numpy f32 order ((x*x+y*y)+z*z), contract OFF —
//                      this value feeds the pinned d2 formula bit-for-bit.
// ---------------------------------------------------------------------------
__global__ __launch_bounds__(256) void prep_kernel(
    const float* __restrict__ feat, const float* __restrict__ xyz,
    float* __restrict__ featT, float4* __restrict__ xyz4)
{
#pragma clang fp contract(off)
    __shared__ float lds[C_F * 65];
    if (blockIdx.x < B_SZ * 128) {
        const int b  = blockIdx.x >> 7;        // 128 n-tiles per batch
        const int n0 = (blockIdx.x & 127) * 64;
        {
            const int c4 = threadIdx.x >> 6;   // 0..3
            const int nn = threadIdx.x & 63;
#pragma unroll
            for (int k = 0; k < 16; ++k) {
                const int c = k * 4 + c4;
                lds[c * 65 + nn] = feat[((size_t)b * C_F + c) * N_PTS + n0 + nn];
            }
        }
        __syncthreads();
        {
            const int n4 = threadIdx.x >> 6;   // 0..3
            const int c  = threadIdx.x & 63;
#pragma unroll
            for (int k = 0; k < 16; ++k) {
                const int nn = k * 4 + n4;
                featT[((size_t)b * N_PTS + n0 + nn) * C_F + c] = lds[c * 65 + nn];
            }
        }
    } else {
        const int i = (blockIdx.x - B_SZ * 128) * 256 + (int)threadIdx.x; // 0..B*N-1
        const float p0 = xyz[i * 3 + 0];
        const float p1 = xyz[i * 3 + 1];
        const float p2 = xyz[i * 3 + 2];
        const float s  = (p0 * p0 + p1 * p1) + p2 * p2;   // np.sum order, no fma
        xyz4[i] = make_float4(p0, p1, p2, s);
    }
}

// ---------------------------------------------------------------------------
// K2: fused ball-query + gather. Block = 256 threads = 4 waves = 4 queries.
//
// Scan phase (per wave): macro-chunks of 256 points, 4 dwordx4 loads issued
// up front, then 4 ballot/compact rounds; early-exit at 32 hits (wave-uniform
// cnt). Hit indices land in LDS sidx[w][*] — no global idx round-trip.
// NUMERICS (pinned, rounds 2-3 passed absmax=0): d2 = (q2 + p2sum) - 2*qp,
// all partials left-to-right f32, contract OFF, bit-matching numpy.
//
// Gather phase (whole block, per query sequentially): 8 lanes/sample read
// featT[b,n,:] as 2 float4s (fully-used 64B lines), stage into LDS stride 33
// (~2-way bank = free), then 536 float4 global stores (obase 128B-aligned).
// Co-schedule win: heavy-tail scan blocks (full 8192-pt scan) hide under
// other blocks' BW-bound output stores.
// ---------------------------------------------------------------------------
__global__ __launch_bounds__(256) void qbg_kernel(
    const float4* __restrict__ xyz4, const float* __restrict__ nxyz,
    const float* __restrict__ featT, float* __restrict__ out)
{
#pragma clang fp contract(off)
    __shared__ int   sidx[4][NS];
    __shared__ float stage[67 * 33];

    const int lane = threadIdx.x & 63;
    const int w    = threadIdx.x >> 6;            // wave id 0..3
    const int q    = blockIdx.x * 4 + w;          // this wave's query
    const int b    = q >> 11;                     // M_Q = 2048
    const float4* __restrict__ xb = xyz4 + (size_t)b * N_PTS;

    {
        const float* __restrict__ qp = nxyz + (size_t)q * 3;
        const float qx = qp[0], qy = qp[1], qz = qp[2];
        const float q2 = (qx * qx + qy * qy) + qz * qz;   // np.sum order

        int  cnt = 0;
        int  first_idx = 0;
        bool have_first = false;

        for (int base = 0; base < N_PTS && cnt < NS; base += 256) {
            float4 P[4];
#pragma unroll
            for (int cc = 0; cc < 4; ++cc)
                P[cc] = xb[base + cc * 64 + lane];
#pragma unroll
            for (int cc = 0; cc < 4; ++cc) {
                if (cnt >= NS) break;                       // wave-uniform
                const float qpdot = (qx * P[cc].x + qy * P[cc].y) + qz * P[cc].z;
                const float d2 = (q2 + P[cc].w) - 2.0f * qpdot;   // ref formula
                const bool pred = d2 < 1.0f;
                const unsigned long long mask = __ballot(pred);
                if (mask) {
                    if (!have_first) {
                        first_idx = base + cc * 64 + __ffsll(mask) - 1;
                        have_first = true;
                    }
                    if (pred) {
                        const int pos = cnt + (int)__popcll(mask & ((1ull << lane) - 1ull));
                        if (pos < NS) sidx[w][pos] = base + cc * 64 + lane;
                    }
                    cnt += (int)__popcll(mask);
                }
            }
        }
        if (cnt < NS) {
            for (int p = cnt + lane; p < NS; p += 64) sidx[w][p] = first_idx;
        }
    }
    __syncthreads();

    // ---- gather phase: 4 queries, sequentially, whole block each ----
    const int pS = threadIdx.x >> 3;              // sample 0..31
    const int j  = threadIdx.x & 7;               // lane-within-sample
    const size_t cstride = (size_t)M_Q * NS;      // 65536

    for (int w2 = 0; w2 < 4; ++w2) {
        const int qq = blockIdx.x * 4 + w2;
        const int mm = qq & (M_Q - 1);
        const int n  = sidx[w2][pS];

        const float* __restrict__ fb = featT + ((size_t)b * N_PTS + n) * C_F;
#pragma unroll
        for (int k = 0; k < 2; ++k) {
            const int c = k * 32 + j * 4;                    // 16B-aligned
            const float4 v = *(const float4*)(fb + c);
            stage[(3 + c + 0) * 33 + pS] = v.x;
            stage[(3 + c + 1) * 33 + pS] = v.y;
            stage[(3 + c + 2) * 33 + pS] = v.z;
            stage[(3 + c + 3) * 33 + pS] = v.w;
        }
        if (j == 0) {
            const float4 pv = xb[n];
            const float* __restrict__ qp2 = nxyz + (size_t)qq * 3;
            stage[0 * 33 + pS] = pv.x - qp2[0];
            stage[1 * 33 + pS] = pv.y - qp2[1];
            stage[2 * 33 + pS] = pv.z - qp2[2];
        }
        __syncthreads();

        // 67 rows x 8 float4 = 536 vector stores; LDS reads scalar (stride 33
        // keeps them ~2-way = free), global stores dwordx4 (16B-aligned).
        const size_t obase = ((size_t)b * 67 * M_Q + mm) * NS;
#pragma unroll
        for (int it = 0; it < 3; ++it) {
            const int e = it * 256 + (int)threadIdx.x;
            if (e < 67 * 8) {
                const int row  = e >> 3;
                const int col4 = (e & 7) * 4;
                float4 v;
                v.x = stage[row * 33 + col4 + 0];
                v.y = stage[row * 33 + col4 + 1];
                v.z = stage[row * 33 + col4 + 2];
                v.w = stage[row * 33 + col4 + 3];
                *(float4*)&out[obase + (size_t)row * cstride + col4] = v;
            }
        }
        __syncthreads();   // stage reused next w2
    }
}

extern "C" void kernel_launch(void* const* d_in, const int* in_sizes, int n_in,
                              void* d_out, int out_size, void* d_ws, size_t ws_size,
                              hipStream_t stream)
{
    const float* xyz  = (const float*)d_in[0];   // (B, N, 3)
    const float* nxyz = (const float*)d_in[1];   // (B, M, 3)
    const float* feat = (const float*)d_in[2];   // (B, C, N)
    float* out = (float*)d_out;                  // (B, 67, M, 32)

    float*  featT = (float*)d_ws;                             // 16.8 MB
    float4* xyz4  = (float4*)((char*)d_ws + (20 << 20));      // 1 MB

    const int Q = B_SZ * M_Q;                    // 16384 queries

    prep_kernel<<<B_SZ * 128 + (B_SZ * N_PTS) / 256, 256, 0, stream>>>(
        feat, xyz, featT, xyz4);
    qbg_kernel<<<Q / 4, 256, 0, stream>>>(xyz4, nxyz, featT, out);
}